// Round 1
// baseline (29.205 us; speedup 1.0000x reference)
//
#include <hip/hip_runtime.h>
#include <hip/hip_bf16.h>
#include <stdint.h>

#define BSZ 8
#define NV 4096
#define NNB 16
#define NCH 64
#define KSLOT 17
#define MT 64
#define LDR 72   // padded LDS row length in bf16 elems (64 + 8 pad = 144 B)

typedef __attribute__((ext_vector_type(8))) short bf16x8;
typedef __attribute__((ext_vector_type(4))) float f32x4;

__device__ __forceinline__ unsigned short f2bf(float f) {
  union { float f; unsigned int u; } v; v.f = f;
  unsigned int r = v.u + 0x7FFF + ((v.u >> 16) & 1);  // RNE
  return (unsigned short)(r >> 16);
}

// feature_map f32 -> bf16 (fmb), 4 elems/thread
__global__ void prep_fm(const float* __restrict__ fm, unsigned short* __restrict__ fmb) {
  int i = (blockIdx.x * blockDim.x + threadIdx.x) * 4;
  float4 v = *(const float4*)(fm + i);
  ushort4 o;
  o.x = f2bf(v.x); o.y = f2bf(v.y); o.z = f2bf(v.z); o.w = f2bf(v.w);
  *(ushort4*)(fmb + i) = o;
}

// weights (64 x 1088, f = c*17+k) -> Wb[k][o][c] bf16
__global__ void prep_w(const float* __restrict__ w, unsigned short* __restrict__ wb) {
  int t = blockIdx.x * blockDim.x + threadIdx.x; // 0..69631 (= 17*64*64)
  int c = t & 63;
  int o = (t >> 6) & 63;
  int k = t >> 12;
  wb[t] = f2bf(w[o * 1088 + c * 17 + k]);
}

__global__ __launch_bounds__(256, 2)
void conv_main(const int* __restrict__ nbr, const unsigned short* __restrict__ fmb,
               const unsigned short* __restrict__ wb, const float* __restrict__ bias,
               float* __restrict__ out) {
  __shared__ unsigned short sA[2][MT][LDR];
  __shared__ unsigned short sB[2][64][LDR];
  __shared__ int sIdx[MT][NNB];
  __shared__ float sBias[64];

  const int tid = threadIdx.x;
  const int b = blockIdx.x >> 6;              // 8 batches
  const int vbase = (blockIdx.x & 63) * MT;   // 64 vertex tiles per batch

  // idx tile: 64 v x 16 n ints = 256 int4, one per thread (coalesced)
  {
    const int4* src = (const int4*)(nbr + ((size_t)b * NV + vbase) * NNB);
    ((int4*)sIdx)[tid] = src[tid];
  }
  if (tid < 64) sBias[tid] = bias[tid];

  const int row = tid >> 3;  // 0..31
  const int seg = tid & 7;   // 16B segment within a 128B row

  auto stageA = [&](int buf, int k) {
    #pragma unroll
    for (int rr = 0; rr < 2; ++rr) {
      int r = row + rr * 32;
      int sv = (k == 0) ? (vbase + r) : sIdx[r][k - 1];
      const uint4* src = (const uint4*)(fmb + ((size_t)b * NV + sv) * NCH);
      *(uint4*)&sA[buf][r][seg * 8] = src[seg];
    }
  };
  auto stageB = [&](int buf, int k) {
    const uint4* src = (const uint4*)(wb + (size_t)k * 64 * 64);
    #pragma unroll
    for (int rr = 0; rr < 2; ++rr) {
      int r = row + rr * 32;
      *(uint4*)&sB[buf][r][seg * 8] = src[r * 8 + seg];
    }
  };

  const int wv = tid >> 6;     // wave 0..3 -> M-subtile
  const int lane = tid & 63;
  const int lm = lane & 15;
  const int lk = lane >> 4;    // 0..3

  f32x4 acc[4] = {f32x4{0,0,0,0}, f32x4{0,0,0,0}, f32x4{0,0,0,0}, f32x4{0,0,0,0}};

  stageA(0, 0); stageB(0, 0);
  __syncthreads();

  for (int k = 0; k < KSLOT; ++k) {
    int buf = k & 1;
    if (k + 1 < KSLOT) { stageA(buf ^ 1, k + 1); stageB(buf ^ 1, k + 1); }
    #pragma unroll
    for (int h = 0; h < 2; ++h) {
      bf16x8 a = *(const bf16x8*)&sA[buf][wv * 16 + lm][h * 32 + lk * 8];
      #pragma unroll
      for (int n = 0; n < 4; ++n) {
        bf16x8 bf = *(const bf16x8*)&sB[buf][n * 16 + lm][h * 32 + lk * 8];
        acc[n] = __builtin_amdgcn_mfma_f32_16x16x32_bf16(a, bf, acc[n], 0, 0, 0);
      }
    }
    __syncthreads();
  }

  // C/D layout: col = lane&15 (out channel within n-tile), row = lk*4 + r (vertex)
  const int gv = vbase + wv * 16 + lk * 4;
  float* op = out + (size_t)b * NV * 64;
  #pragma unroll
  for (int n = 0; n < 4; ++n) {
    int o = n * 16 + lm;
    float bv = sBias[o];
    #pragma unroll
    for (int r = 0; r < 4; ++r) {
      float x = acc[n][r] + bv;
      op[(size_t)(gv + r) * 64 + o] = fmaxf(x, 0.f);
    }
  }
}

extern "C" void kernel_launch(void* const* d_in, const int* in_sizes, int n_in,
                              void* d_out, int out_size, void* d_ws, size_t ws_size,
                              hipStream_t stream) {
  const int* nbr = (const int*)d_in[0];
  // d_in[1] = vertices (unused by the reference computation)
  const float* fm = (const float*)d_in[2];
  const float* w = (const float*)d_in[3];
  const float* bias = (const float*)d_in[4];
  float* out = (float*)d_out;

  unsigned short* fmb = (unsigned short*)d_ws;                 // 2,097,152 bf16
  unsigned short* wb = fmb + (size_t)BSZ * NV * NCH;           // 69,632 bf16

  prep_fm<<<2048, 256, 0, stream>>>(fm, fmb);
  prep_w<<<272, 256, 0, stream>>>(w, wb);
  conv_main<<<512, 256, 0, stream>>>(nbr, fmb, wb, bias, out);
}